// Round 4
// baseline (39.894 us; speedup 1.0000x reference)
//
#include <hip/hip_runtime.h>

// Grouped conv1d over W + roll(+1) along H, bf16 MFMA.
// x: (128, 48, 28, 28) f32, channel = g*24+ci
// w: (24, 96, 7) f32, w[ci][o][k], shared across the 2 groups
// out: (128, 192, 28, 28) f32, channel = g*96+o
//
// GEMM per (b, hquad, g): M=112 (4 h-rows x 28 W), N=96, K=168 pad 192.
// k-axis PERMUTATION (must match between A and B):
//   hw slot = ks*32 + kgrp*8 + j, q = ks*4+kgrp (0..23)
//   q<21: k = q/3, ci = (q%3)*8 + j ; q>=21: zero (enforced on B side only)
//
// R4: no W-LDS staging (B-frags are L1/L2-hot global loads, same 36KB for all
// blocks), no epilogue transpose (R2 measured scatter-store amplification at
// only 7.8%). LDS = 6.9KB xs only; 1 barrier per block.

typedef __attribute__((ext_vector_type(8))) short short8;
typedef __attribute__((ext_vector_type(4))) float float4v;

#define B_     128
#define H_     28
#define W_     28
#define CIN_   24
#define COUT_  96
#define K_     7
#define KSTEPS 6
#define NT_    6

// float -> bf16 bits, RNE
static __device__ __forceinline__ unsigned f2bf_u(float f) {
    union { float f; unsigned u; } v; v.f = f;
    return (v.u + 0x7fffu + ((v.u >> 16) & 1u)) >> 16;
}
static __device__ __forceinline__ short f2bf(float f) { return (short)f2bf_u(f); }

// Pre-pack weights into B-fragment order with the permuted k-axis.
// B-frag (16x16x32): lane l holds B[hw=(l>>4)*8+j][col=l&15], j=0..7
__global__ __launch_bounds__(64)
void wfrag_kernel(const float* __restrict__ w, short8* __restrict__ wf) {
    const int idx  = blockIdx.x;          // 0..35 = ks*6 + nt
    const int ks   = idx / 6, nt = idx - ks * 6;
    const int lane = threadIdx.x;
    const int c    = nt * 16 + (lane & 15);
    const int q    = ks * 4 + (lane >> 4);
    short8 v;
    if (q < 21) {
        const int k   = (q * 11) >> 5;    // q/3 for q in 0..23
        const int ci0 = (q - 3 * k) * 8;
#pragma unroll
        for (int j = 0; j < 8; ++j)
            v[j] = f2bf(w[(ci0 + j) * (COUT_ * K_) + c * K_ + k]);
    } else {
#pragma unroll
        for (int j = 0; j < 8; ++j) v[j] = 0;   // zero-pad: makes A garbage harmless
    }
    wf[idx * 64 + lane] = v;
}

__global__ __launch_bounds__(448, 6)
void conv_mfma_kernel(const float* __restrict__ x,
                      const short8* __restrict__ wfg,
                      float* __restrict__ out) {
    const int bid = blockIdx.x;           // 128*7*2 = 1792
    const int g   = bid & 1;
    const int hq  = (bid >> 1) % 7;
    const int b   = bid / 14;
    const int h0  = hq * 4;
    const int tid = threadIdx.x;

    // xs[hl][p][ci] bf16, p = t+3 padded coord. 4*36*24*2 = 6912 B.
    __shared__ __align__(16) short xs[4 * 36 * 24];

    for (int idx = tid; idx < 4 * 12 * 36; idx += 448) {
        const int p  = idx % 36;
        const int t2 = idx / 36;
        const int cp = t2 % 12;           // ci pair
        const int hl = t2 / 12;
        const int ws = p - 3;
        float v0 = 0.0f, v1 = 0.0f;
        if (ws >= 0 && ws < W_) {
            const size_t base = ((size_t)(b * 48 + g * CIN_ + cp * 2) * H_ + (h0 + hl)) * W_ + ws;
            v0 = x[base];
            v1 = x[base + (size_t)H_ * W_];
        }
        ((unsigned*)xs)[(hl * 36 + p) * 12 + cp] = f2bf_u(v0) | (f2bf_u(v1) << 16);
    }
    __syncthreads();

    const int lane = tid & 63;
    const int wv   = tid >> 6;            // 0..6 : M-tile
    const int cgrp = lane & 15;
    const int kgrp = lane >> 4;

    // A-frag row for this lane
    const int mA = wv * 16 + cgrp;        // 0..111
    const int hA = mA / 28;
    const int tA = mA - hA * 28;

    // Per-ks A short-index (8 contiguous bf16 -> one ds_read_b128)
    int sidx[KSTEPS];
#pragma unroll
    for (int ks = 0; ks < KSTEPS; ++ks) {
        const int q   = ks * 4 + kgrp;
        const int k   = (q * 11) >> 5;
        const int ci0 = (q - 3 * k) * 8;
        sidx[ks] = (hA * 36 + tA + k) * 24 + ci0;   // 16B-aligned
    }

    float4v acc[NT_];
#pragma unroll
    for (int i = 0; i < NT_; ++i) acc[i] = (float4v)(0.0f);

#pragma unroll
    for (int ks = 0; ks < KSTEPS; ++ks) {
        const short8 a = *(const short8*)&xs[sidx[ks]];
        short8 br[NT_];
#pragma unroll
        for (int nt = 0; nt < NT_; ++nt)
            br[nt] = wfg[(ks * NT_ + nt) * 64 + lane];   // L1/L2-hot, pipelined
#pragma unroll
        for (int nt = 0; nt < NT_; ++nt)
            acc[nt] = __builtin_amdgcn_mfma_f32_16x16x32_bf16(a, br[nt], acc[nt], 0, 0, 0);
    }

    // Direct scatter epilogue (no barriers). D layout: row m = wv*16+kgrp*4+j,
    // col = lane&15. Per channel each block covers a contiguous 448B span, so
    // L2 write-combines (R2: 7.8% amplification).
    int offj[4];
#pragma unroll
    for (int j = 0; j < 4; ++j) {
        const int m  = wv * 16 + kgrp * 4 + j;
        const int hl = m / 28;
        const int t  = m - hl * 28;
        int hd = h0 + hl + 1; if (hd >= H_) hd -= H_;   // roll(+1)
        offj[j] = hd * W_ + t;
    }
    float* cbase = out + ((size_t)(b * 192 + g * COUT_ + cgrp)) * (H_ * W_);
#pragma unroll
    for (int nt = 0; nt < NT_; ++nt) {
#pragma unroll
        for (int j = 0; j < 4; ++j)
            cbase[nt * 16 * (H_ * W_) + offj[j]] = acc[nt][j];
    }
}

extern "C" void kernel_launch(void* const* d_in, const int* in_sizes, int n_in,
                              void* d_out, int out_size, void* d_ws, size_t ws_size,
                              hipStream_t stream) {
    const float* x = (const float*)d_in[0];
    const float* w = (const float*)d_in[1];
    float* out = (float*)d_out;
    short8* wf = (short8*)d_ws;           // 36*64*16B = 36864 B

    wfrag_kernel<<<36, 64, 0, stream>>>(w, wf);
    conv_mfma_kernel<<<B_ * 7 * 2, 448, 0, stream>>>(x, wf, out);
}

// Round 5
// 38.142 us; speedup vs baseline: 1.0459x; 1.0459x over previous
//
#include <hip/hip_runtime.h>

// Grouped conv1d over W + roll(+1) along H, bf16 MFMA.
// x: (128, 48, 28, 28) f32, channel = g*24+ci
// w: (24, 96, 7) f32, w[ci][o][k], shared across the 2 groups
// out: (128, 192, 28, 28) f32, channel = g*96+o
//
// GEMM per (b, hquad, g): M=112 (4 h-rows x 28 W), N=96, K=168 pad 192.
// k-axis PERMUTATION (must match between A and B):
//   hw slot = ks*32 + kgrp*8 + j, q = ks*4+kgrp (0..23)
//   q<21: k = q/3, ci = (q%3)*8 + j ; q>=21: zero (enforced on B side only)
//
// R5: wave = one N-tile -> entire B operand is 6 frags = 24 VGPR, loaded ONCE
// pre-barrier (R4 lesson: in-loop global B loads never pipeline). Hot loop is
// pure ds_read_b128 + MFMA. LDS = 6.9KB xs only; 1 barrier; scatter epilogue
// (measured amplification only 7-9%).

typedef __attribute__((ext_vector_type(8))) short short8;
typedef __attribute__((ext_vector_type(4))) float float4v;

#define B_     128
#define H_     28
#define W_     28
#define CIN_   24
#define COUT_  96
#define K_     7
#define KSTEPS 6
#define NT_    6
#define MT_    7

// float -> bf16 bits, RNE
static __device__ __forceinline__ unsigned f2bf_u(float f) {
    union { float f; unsigned u; } v; v.f = f;
    return (v.u + 0x7fffu + ((v.u >> 16) & 1u)) >> 16;
}
static __device__ __forceinline__ short f2bf(float f) { return (short)f2bf_u(f); }

// Pre-pack weights into B-fragment order with the permuted k-axis.
// B-frag (16x16x32): lane l holds B[hw=(l>>4)*8+j][col=l&15], j=0..7
__global__ __launch_bounds__(64)
void wfrag_kernel(const float* __restrict__ w, short8* __restrict__ wf) {
    const int idx  = blockIdx.x;          // 0..35 = ks*6 + nt
    const int ks   = idx / 6, nt = idx - ks * 6;
    const int lane = threadIdx.x;
    const int c    = nt * 16 + (lane & 15);
    const int q    = ks * 4 + (lane >> 4);
    short8 v;
    if (q < 21) {
        const int k   = (q * 11) >> 5;    // q/3 for q in 0..23
        const int ci0 = (q - 3 * k) * 8;
#pragma unroll
        for (int j = 0; j < 8; ++j)
            v[j] = f2bf(w[(ci0 + j) * (COUT_ * K_) + c * K_ + k]);
    } else {
#pragma unroll
        for (int j = 0; j < 8; ++j) v[j] = 0;   // zero-pad: makes A garbage harmless
    }
    wf[idx * 64 + lane] = v;
}

__global__ __launch_bounds__(384, 4)
void conv_mfma_kernel(const float* __restrict__ x,
                      const short8* __restrict__ wfg,
                      float* __restrict__ out) {
    const int bid = blockIdx.x;           // 128*7*2 = 1792
    const int g   = bid & 1;
    const int hq  = (bid >> 1) % 7;
    const int b   = bid / 14;
    const int h0  = hq * 4;
    const int tid = threadIdx.x;

    // xs[hl][p][ci] bf16, p = t+3 padded coord. 4*36*24*2 = 6912 B.
    __shared__ __align__(16) short xs[4 * 36 * 24];

    const int lane = tid & 63;
    const int nt   = tid >> 6;            // wave = N-tile, 0..5
    const int cgrp = lane & 15;
    const int kgrp = lane >> 4;

    // Entire B operand for this wave: 6 frags = 24 VGPR, loaded once (L2-hot,
    // issued before the barrier -> fully overlapped with x staging).
    short8 br[KSTEPS];
#pragma unroll
    for (int ks = 0; ks < KSTEPS; ++ks)
        br[ks] = wfg[(ks * NT_ + nt) * 64 + lane];

    // Stage x as bf16 pairs into xs[hl][p][ci] (p = t+3 padded coord)
    for (int idx = tid; idx < 4 * 12 * 36; idx += 384) {
        const int p  = idx % 36;
        const int t2 = idx / 36;
        const int cp = t2 % 12;           // ci pair
        const int hl = t2 / 12;
        const int ws = p - 3;
        float v0 = 0.0f, v1 = 0.0f;
        if (ws >= 0 && ws < W_) {
            const size_t base = ((size_t)(b * 48 + g * CIN_ + cp * 2) * H_ + (h0 + hl)) * W_ + ws;
            v0 = x[base];
            v1 = x[base + (size_t)H_ * W_];
        }
        ((unsigned*)xs)[(hl * 36 + p) * 12 + cp] = f2bf_u(v0) | (f2bf_u(v1) << 16);
    }
    __syncthreads();

    // Per-lane k/ci for each k-step (A and B share the permutation)
    int koff[KSTEPS];
#pragma unroll
    for (int ks = 0; ks < KSTEPS; ++ks) {
        const int q   = ks * 4 + kgrp;
        const int k   = (q * 11) >> 5;
        const int ci0 = (q - 3 * k) * 8;
        koff[ks] = k * 24 + ci0;          // add (hA*36+tA)*24
    }

    float* cbase = out + ((size_t)(b * 192 + g * COUT_ + nt * 16 + cgrp)) * (H_ * W_);

#pragma unroll
    for (int mt = 0; mt < MT_; ++mt) {
        const int mA = mt * 16 + cgrp;
        const int hA = mA / 28;
        const int tA = mA - hA * 28;
        const int abase = (hA * 36 + tA) * 24;

        float4v acc = (float4v)(0.0f);
#pragma unroll
        for (int ks = 0; ks < KSTEPS; ++ks) {
            const short8 a = *(const short8*)&xs[abase + koff[ks]];
            acc = __builtin_amdgcn_mfma_f32_16x16x32_bf16(a, br[ks], acc, 0, 0, 0);
        }

        // D layout: row m = mt*16 + kgrp*4 + j, col = cgrp (our channel)
#pragma unroll
        for (int j = 0; j < 4; ++j) {
            const int m  = mt * 16 + kgrp * 4 + j;
            const int hl = m / 28;
            const int t  = m - hl * 28;
            int hd = h0 + hl + 1; if (hd >= H_) hd -= H_;   // roll(+1)
            cbase[hd * W_ + t] = acc[j];
        }
    }
}

extern "C" void kernel_launch(void* const* d_in, const int* in_sizes, int n_in,
                              void* d_out, int out_size, void* d_ws, size_t ws_size,
                              hipStream_t stream) {
    const float* x = (const float*)d_in[0];
    const float* w = (const float*)d_in[1];
    float* out = (float*)d_out;
    short8* wf = (short8*)d_ws;           // 36*64*16B = 36864 B

    wfrag_kernel<<<36, 64, 0, stream>>>(w, wf);
    conv_mfma_kernel<<<B_ * 7 * 2, 384, 0, stream>>>(x, wf, out);
}